// Round 17
// baseline (608.868 us; speedup 1.0000x reference)
//
#include <hip/hip_runtime.h>
#include <math.h>

constexpr int NN = 40000;
constexpr int NE = 640000;
constexpr int KD = 129;     // contraction dim (time + 128 space)

constexpr float LOG2E = 1.4426950408889634f;
constexpr float SC_C  = 0.35355339059327373f * LOG2E;   // 2/sqrt(32) * log2(e)

// ---- transposed-weight buffer offsets (in floats) ----
constexpr int OFF_IN   = 0;
constexpr int OFF_QKV0 = OFF_IN   + KD*128;
constexpr int OFF_QKV1 = OFF_QKV0 + KD*384;
constexpr int OFF_OUT0 = OFF_QKV1 + KD*384;
constexpr int OFF_OUT1 = OFF_OUT0 + KD*128;
constexpr int OFF_OUTP = OFF_OUT1 + KD*128;
constexpr int WT_TOTAL = OFF_OUTP + KD*128;   // 165120 floats

struct QkvPtrs {
  float* sp0; float* tp0;
  float* sp1; float* tp1;
  float* sp2; float* tp2;
};

// =================== small utility kernels ===================

__global__ void zero_i32(int* p, int n) {
  int i = blockIdx.x * 256 + threadIdx.x;
  if (i < n) p[i] = 0;
}

// transpose all weights to k-major once per call
__global__ void prep_wt(const float* __restrict__ in_w, const float* __restrict__ q_w,
                        const float* __restrict__ k_w, const float* __restrict__ v_w,
                        const float* __restrict__ out_w, const float* __restrict__ outp_w,
                        float* __restrict__ WT) {
  int t = blockIdx.x * 256 + threadIdx.x;
  if (t >= KD * 1280) return;
  int k = t / 1280, c = t % 1280;
  float v; int dst;
  if (c < 128) {
    v = in_w[(size_t)c * KD + k];
    dst = OFF_IN + k * 128 + c;
  } else if (c < 896) {
    int l = (c - 128) / 384, cc = (c - 128) % 384;
    int arr = cc >> 7, r = cc & 127;
    const float* w = arr == 0 ? q_w : (arr == 1 ? k_w : v_w);
    v = w[((size_t)l * 128 + r) * KD + k];
    dst = (l == 0 ? OFF_QKV0 : OFF_QKV1) + k * 384 + cc;
  } else if (c < 1152) {
    int l = (c - 896) / 128, r = (c - 896) % 128;
    v = out_w[((size_t)l * 128 + r) * KD + k];
    dst = (l == 0 ? OFF_OUT0 : OFF_OUT1) + k * 128 + r;
  } else {
    int r = c - 1152;
    v = outp_w[(size_t)r * KD + k];
    dst = OFF_OUTP + k * 128 + r;
  }
  WT[dst] = v;
}

__global__ void prep_bias(const float* __restrict__ q_b, const float* __restrict__ k_b,
                          const float* __restrict__ v_b, float* __restrict__ bq) {
  int t = blockIdx.x * 256 + threadIdx.x;
  if (t >= 768) return;
  int l = t / 384, c = t % 384;
  int arr = c >> 7, r = c & 127;
  const float* b = arr == 0 ? q_b : (arr == 1 ? k_b : v_b);
  bq[t] = b[l * 128 + r];
}

// =================== CSR build ===================

__global__ void count_kernel(const int* __restrict__ dst, int* __restrict__ counts, int E) {
  int e = blockIdx.x * 256 + threadIdx.x;
  if (e < E) atomicAdd(&counts[dst[e]], 1);
}

// ---- 3-phase parallel scan ----
__global__ __launch_bounds__(1024) void scan_bsum(const int* __restrict__ counts,
                                                  int* __restrict__ bsum) {
  __shared__ int ws[16];
  int b = blockIdx.x, tid = threadIdx.x;
  int idx = b * 1024 + tid;
  int v = (idx < NN) ? counts[idx] : 0;
  #pragma unroll
  for (int off = 1; off < 64; off <<= 1) v += __shfl_xor(v, off);
  if ((tid & 63) == 0) ws[tid >> 6] = v;
  __syncthreads();
  if (tid < 16) {
    int t = ws[tid];
    #pragma unroll
    for (int off = 1; off < 16; off <<= 1) t += __shfl_xor(t, off);
    if (tid == 0) bsum[b] = t;
  }
}

__global__ void scan_boff(const int* __restrict__ bsum, int* __restrict__ boff, int nb) {
  int tid = threadIdx.x;
  int v = (tid < nb) ? bsum[tid] : 0;
  int s = v;
  #pragma unroll
  for (int off = 1; off < 64; off <<= 1) {
    int t = __shfl_up(s, off);
    if (tid >= off) s += t;
  }
  if (tid < nb) boff[tid] = s - v;   // exclusive
}

__global__ __launch_bounds__(1024) void scan_final(const int* __restrict__ counts,
                                                   const int* __restrict__ boff,
                                                   int* __restrict__ ro) {
  __shared__ int wsum[16];
  int b = blockIdx.x, tid = threadIdx.x, wid = tid >> 6, lane = tid & 63;
  int idx = b * 1024 + tid;
  int v = (idx < NN) ? counts[idx] : 0;
  int s = v;
  #pragma unroll
  for (int off = 1; off < 64; off <<= 1) {
    int t = __shfl_up(s, off);
    if (lane >= off) s += t;
  }
  if (lane == 63) wsum[wid] = s;
  __syncthreads();
  if (wid == 0) {
    int ws = (lane < 16) ? wsum[lane] : 0;
    #pragma unroll
    for (int off = 1; off < 16; off <<= 1) {
      int t = __shfl_up(ws, off);
      if (lane >= off) ws += t;
    }
    if (lane < 16) wsum[lane] = ws;
  }
  __syncthreads();
  int woff = (wid > 0) ? wsum[wid - 1] : 0;
  if (idx < NN) ro[idx + 1] = s + woff + boff[b];
  if (b == 0 && tid == 0) ro[0] = 0;
}

// also emits inv_e: CSR position of each original edge id
__global__ void scatter_kernel(const int* __restrict__ src, const int* __restrict__ dst,
                               const int* __restrict__ ro, int* __restrict__ cursor,
                               int* __restrict__ s_csr, int* __restrict__ inv_e, int E) {
  int e = blockIdx.x * 256 + threadIdx.x;
  if (e >= E) return;
  int d = dst[e];
  int pos = ro[d] + atomicAdd(&cursor[d], 1);
  s_csr[pos] = src[e];
  inv_e[e] = pos;
}

// =================== edge-bias precompute (both layers, CSR-ordered out) ===================
__global__ __launch_bounds__(256) void ebias_kernel(const float* __restrict__ ef,
                                                    const float* __restrict__ ebw,
                                                    const int* __restrict__ inv_e,
                                                    float* __restrict__ eb) {
  __shared__ float w[128];
  if (threadIdx.x < 128) w[threadIdx.x] = ebw[threadIdx.x];
  __syncthreads();
  int e = blockIdx.x * 256 + threadIdx.x;
  if (e >= NE) return;
  float f[16];
  #pragma unroll
  for (int i = 0; i < 4; i++) *(float4*)&f[i * 4] = *(const float4*)(ef + (size_t)e * 16 + i * 4);
  int pos = inv_e[e];
  #pragma unroll
  for (int l = 0; l < 2; l++) {
    float4 o;
    float* op = &o.x;
    #pragma unroll
    for (int h = 0; h < 4; h++) {
      float acc = 0.f;
      #pragma unroll
      for (int i = 0; i < 16; i++) acc = fmaf(f[i], w[l * 64 + h * 16 + i], acc);
      op[h] = fmaf(acc, LOG2E, SC_C);
    }
    *(float4*)(eb + (size_t)l * NE * 4 + (size_t)pos * 4) = o;
  }
}

// =================== expmap0 ===================
__global__ void expmap_kernel(const float* __restrict__ x, float* __restrict__ hs,
                              float* __restrict__ ht) {
  int nl = threadIdx.x >> 6, lane = threadIdx.x & 63;
  int n = blockIdx.x * 4 + nl;
  if (n >= NN) return;
  const float* xr = x + (size_t)n * 128;
  float v0 = xr[lane], v1 = xr[lane + 64];
  float ss = v0 * v0 + v1 * v1;
  #pragma unroll
  for (int off = 1; off < 64; off <<= 1) ss += __shfl_xor(ss, off);
  float nn = sqrtf(fmaxf(ss, 1e-12f));
  float s = sinhf(nn) / nn;
  float* hr = hs + (size_t)n * 128;
  if (lane == 0) ht[n] = coshf(nn);
  hr[lane] = s * v0;
  hr[lane + 64] = s * v1;
}

// =================== node GEMM (EPI 0/2/3): 2 nodes x 32 cols per thread ===================
template<int EPI>
__global__ __launch_bounds__(256, 3) void node_gemm(
    const float* __restrict__ As, const float* __restrict__ At,
    const float* __restrict__ WT, int outc,
    const float* __restrict__ bias,
    float* __restrict__ outS, float* __restrict__ outT,
    const float* __restrict__ resS, const float* __restrict__ resT,
    const float* __restrict__ gv, const float* __restrict__ bvv) {
  __shared__ float red[2][128][5];
  const int tid = threadIdx.x;
  const int ln = tid & 63;
  const int grp = __builtin_amdgcn_readfirstlane(tid >> 6);
  const int n0 = blockIdx.x * 128 + ln;
  const bool has1 = (n0 + 64) < NN;
  const int n1 = has1 ? (n0 + 64) : n0;
  const int c0 = grp << 5;

  float acc0[32], acc1[32];
  { // k = 0 (time row) folded into init together with bias
    float at0 = At[n0];
    float at1 = At[n1];
    const float* w0 = WT + c0;
    #pragma unroll
    for (int i = 0; i < 8; i++) {
      float4 b4 = *(const float4*)(bias + c0 + i * 4);
      float4 w4 = *(const float4*)(w0 + i * 4);
      acc0[i * 4 + 0] = fmaf(at0, w4.x, b4.x);
      acc0[i * 4 + 1] = fmaf(at0, w4.y, b4.y);
      acc0[i * 4 + 2] = fmaf(at0, w4.z, b4.z);
      acc0[i * 4 + 3] = fmaf(at0, w4.w, b4.w);
      acc1[i * 4 + 0] = fmaf(at1, w4.x, b4.x);
      acc1[i * 4 + 1] = fmaf(at1, w4.y, b4.y);
      acc1[i * 4 + 2] = fmaf(at1, w4.z, b4.z);
      acc1[i * 4 + 3] = fmaf(at1, w4.w, b4.w);
    }
  }
  const float* Ar0 = As + (size_t)n0 * 128;
  const float* Ar1 = As + (size_t)n1 * 128;
  for (int k4 = 0; k4 < 32; k4++) {
    float a0[4], a1[4];
    *(float4*)a0 = *(const float4*)(Ar0 + (k4 << 2));
    *(float4*)a1 = *(const float4*)(Ar1 + (k4 << 2));
    #pragma unroll
    for (int kk = 0; kk < 4; kk++) {
      const float* wp = WT + (size_t)(1 + (k4 << 2) + kk) * outc + c0;
      float av0 = a0[kk], av1 = a1[kk];
      #pragma unroll
      for (int i = 0; i < 8; i++) {
        float4 w4 = *(const float4*)(wp + i * 4);
        acc0[i * 4 + 0] = fmaf(av0, w4.x, acc0[i * 4 + 0]);
        acc0[i * 4 + 1] = fmaf(av0, w4.y, acc0[i * 4 + 1]);
        acc0[i * 4 + 2] = fmaf(av0, w4.z, acc0[i * 4 + 2]);
        acc0[i * 4 + 3] = fmaf(av0, w4.w, acc0[i * 4 + 3]);
        acc1[i * 4 + 0] = fmaf(av1, w4.x, acc1[i * 4 + 0]);
        acc1[i * 4 + 1] = fmaf(av1, w4.y, acc1[i * 4 + 1]);
        acc1[i * 4 + 2] = fmaf(av1, w4.z, acc1[i * 4 + 2]);
        acc1[i * 4 + 3] = fmaf(av1, w4.w, acc1[i * 4 + 3]);
      }
    }
  }

  if constexpr (EPI == 0) {           // LayerNorm + ReLU + lift
    float s0 = 0.f, p0 = 0.f, s1 = 0.f, p1 = 0.f;
    #pragma unroll
    for (int j = 0; j < 32; j++) {
      s0 += acc0[j]; p0 += acc0[j] * acc0[j];
      s1 += acc1[j]; p1 += acc1[j] * acc1[j];
    }
    red[0][ln][grp] = s0; red[1][ln][grp] = p0;
    red[0][ln + 64][grp] = s1; red[1][ln + 64][grp] = p1;
    __syncthreads();
    float S0 = 0.f, P0 = 0.f, S1 = 0.f, P1 = 0.f;
    #pragma unroll
    for (int q = 0; q < 4; q++) {
      S0 += red[0][ln][q]; P0 += red[1][ln][q];
      S1 += red[0][ln + 64][q]; P1 += red[1][ln + 64][q];
    }
    float mu0 = S0 * (1.f / 128.f), mu1 = S1 * (1.f / 128.f);
    float rstd0 = 1.f / sqrtf(P0 * (1.f / 128.f) - mu0 * mu0 + 1e-5f);
    float rstd1 = 1.f / sqrtf(P1 * (1.f / 128.f) - mu1 * mu1 + 1e-5f);
    float ss0 = 0.f, ss1 = 0.f;
    #pragma unroll
    for (int j = 0; j < 32; j++) {
      float g = gv[c0 + j], b = bvv[c0 + j];
      float z0 = fmaxf((acc0[j] - mu0) * rstd0 * g + b, 0.f);
      float z1 = fmaxf((acc1[j] - mu1) * rstd1 * g + b, 0.f);
      ss0 += z0 * z0; ss1 += z1 * z1;
      acc0[j] = z0; acc1[j] = z1;
    }
    __syncthreads();
    red[0][ln][grp] = ss0; red[0][ln + 64][grp] = ss1;
    __syncthreads();
    float SS0 = red[0][ln][0] + red[0][ln][1] + red[0][ln][2] + red[0][ln][3];
    float SS1 = red[0][ln + 64][0] + red[0][ln + 64][1] + red[0][ln + 64][2] + red[0][ln + 64][3];
    float* o0 = outS + (size_t)n0 * 128 + c0;
    #pragma unroll
    for (int i = 0; i < 8; i++) *(float4*)(o0 + i * 4) = *(float4*)&acc0[i * 4];
    if (grp == 0) outT[n0] = sqrtf(1.f + SS0);
    if (has1) {
      float* o1 = outS + (size_t)n1 * 128 + c0;
      #pragma unroll
      for (int i = 0; i < 8; i++) *(float4*)(o1 + i * 4) = *(float4*)&acc1[i * 4];
      if (grp == 0) outT[n1] = sqrtf(1.f + SS1);
    }
  } else if constexpr (EPI == 2) {    // lift + midpoint2(res) + LayerNorm + lift
    float sy0 = 0.f, sy1 = 0.f;
    #pragma unroll
    for (int j = 0; j < 32; j++) { sy0 += acc0[j] * acc0[j]; sy1 += acc1[j] * acc1[j]; }
    red[0][ln][grp] = sy0; red[0][ln + 64][grp] = sy1;
    __syncthreads();
    float SY0 = red[0][ln][0] + red[0][ln][1] + red[0][ln][2] + red[0][ln][3];
    float SY1 = red[0][ln + 64][0] + red[0][ln + 64][1] + red[0][ln + 64][2] + red[0][ln + 64][3];
    float a00 = 0.5f * (sqrtf(1.f + SY0) + resT[n0]);
    float a01 = 0.5f * (sqrtf(1.f + SY1) + resT[n1]);
    const float* rr0 = resS + (size_t)n0 * 128 + c0;
    const float* rr1 = resS + (size_t)n1 * 128 + c0;
    float sa0 = 0.f, su0 = 0.f, sa1 = 0.f, su1 = 0.f;
    #pragma unroll
    for (int i = 0; i < 8; i++) {
      float4 r40 = *(const float4*)(rr0 + i * 4);
      float4 r41 = *(const float4*)(rr1 + i * 4);
      const float* rp0 = &r40.x;
      const float* rp1 = &r41.x;
      #pragma unroll
      for (int q = 0; q < 4; q++) {
        float a = 0.5f * (acc0[i * 4 + q] + rp0[q]);
        acc0[i * 4 + q] = a; sa0 += a * a; su0 += a;
        float b = 0.5f * (acc1[i * 4 + q] + rp1[q]);
        acc1[i * 4 + q] = b; sa1 += b * b; su1 += b;
      }
    }
    __syncthreads();
    red[0][ln][grp] = sa0; red[1][ln][grp] = su0;
    red[0][ln + 64][grp] = sa1; red[1][ln + 64][grp] = su1;
    __syncthreads();
    float SA0 = 0.f, SU0 = 0.f, SA1 = 0.f, SU1 = 0.f;
    #pragma unroll
    for (int q = 0; q < 4; q++) {
      SA0 += red[0][ln][q]; SU0 += red[1][ln][q];
      SA1 += red[0][ln + 64][q]; SU1 += red[1][ln + 64][q];
    }
    float inv0 = 1.f / sqrtf(fmaxf(fabsf(a00 * a00 - SA0), 1e-8f));
    float inv1 = 1.f / sqrtf(fmaxf(fabsf(a01 * a01 - SA1), 1e-8f));
    float mu0 = SU0 * inv0 * (1.f / 128.f), mu1 = SU1 * inv1 * (1.f / 128.f);
    float rstd0 = 1.f / sqrtf(SA0 * inv0 * inv0 * (1.f / 128.f) - mu0 * mu0 + 1e-5f);
    float rstd1 = 1.f / sqrtf(SA1 * inv1 * inv1 * (1.f / 128.f) - mu1 * mu1 + 1e-5f);
    float ss0 = 0.f, ss1 = 0.f;
    #pragma unroll
    for (int j = 0; j < 32; j++) {
      float g = gv[c0 + j], b = bvv[c0 + j];
      float z0 = (acc0[j] * inv0 - mu0) * rstd0 * g + b;
      float z1 = (acc1[j] * inv1 - mu1) * rstd1 * g + b;
      ss0 += z0 * z0; ss1 += z1 * z1;
      acc0[j] = z0; acc1[j] = z1;
    }
    __syncthreads();
    red[0][ln][grp] = ss0; red[0][ln + 64][grp] = ss1;
    __syncthreads();
    float SS0 = red[0][ln][0] + red[0][ln][1] + red[0][ln][2] + red[0][ln][3];
    float SS1 = red[0][ln + 64][0] + red[0][ln + 64][1] + red[0][ln + 64][2] + red[0][ln + 64][3];
    float* o0 = outS + (size_t)n0 * 128 + c0;
    #pragma unroll
    for (int i = 0; i < 8; i++) *(float4*)(o0 + i * 4) = *(float4*)&acc0[i * 4];
    if (grp == 0) outT[n0] = sqrtf(1.f + SS0);
    if (has1) {
      float* o1 = outS + (size_t)n1 * 128 + c0;
      #pragma unroll
      for (int i = 0; i < 8; i++) *(float4*)(o1 + i * 4) = *(float4*)&acc1[i * 4];
      if (grp == 0) outT[n1] = sqrtf(1.f + SS1);
    }
  } else {                            // EPI == 3: lift + logmap0 (packed out)
    float s0 = 0.f, s1 = 0.f;
    #pragma unroll
    for (int j = 0; j < 32; j++) { s0 += acc0[j] * acc0[j]; s1 += acc1[j] * acc1[j]; }
    red[0][ln][grp] = s0; red[0][ln + 64][grp] = s1;
    __syncthreads();
    float S0 = red[0][ln][0] + red[0][ln][1] + red[0][ln][2] + red[0][ln][3];
    float S1 = red[0][ln + 64][0] + red[0][ln + 64][1] + red[0][ln + 64][2] + red[0][ln + 64][3];
    float nn0 = sqrtf(fmaxf(S0, 1e-12f));
    float nn1 = sqrtf(fmaxf(S1, 1e-12f));
    float sc0 = acoshf(fmaxf(sqrtf(1.f + S0), 1.f + 1e-7f)) / nn0;
    float sc1 = acoshf(fmaxf(sqrtf(1.f + S1), 1.f + 1e-7f)) / nn1;
    float* o0 = outS + (size_t)n0 * 128 + c0;
    #pragma unroll
    for (int j = 0; j < 32; j++) { acc0[j] *= sc0; acc1[j] *= sc1; }
    #pragma unroll
    for (int i = 0; i < 8; i++) *(float4*)(o0 + i * 4) = *(float4*)&acc0[i * 4];
    if (has1) {
      float* o1 = outS + (size_t)n1 * 128 + c0;
      #pragma unroll
      for (int i = 0; i < 8; i++) *(float4*)(o1 + i * 4) = *(float4*)&acc1[i * 4];
    }
  }
}

// =================== qkv GEMM: 2 nodes x 32 cols per thread (R11 proven) ===================
__global__ __launch_bounds__(256, 3) void qkv_gemm(
    const float* __restrict__ As, const float* __restrict__ At,
    const float* __restrict__ WT, const float* __restrict__ bias,
    QkvPtrs qo) {
  const int tid = threadIdx.x;
  const int ln = tid & 63;
  const int grp = __builtin_amdgcn_readfirstlane(tid >> 6);
  const int n0 = blockIdx.x * 128 + ln;
  const int n1 = n0 + 64;
  const bool has1 = n1 < NN;
  const int cb = blockIdx.y;
  const int colOff = (cb << 7) + (grp << 5);
  constexpr int outc = 384;

  float acc0[32], acc1[32];
  {
    float at0 = At[n0];
    float at1 = has1 ? At[n1] : 0.f;
    const float* w0 = WT + colOff;
    #pragma unroll
    for (int i = 0; i < 8; i++) {
      float4 b4 = *(const float4*)(bias + colOff + i * 4);
      float4 w4 = *(const float4*)(w0 + i * 4);
      acc0[i * 4 + 0] = fmaf(at0, w4.x, b4.x);
      acc0[i * 4 + 1] = fmaf(at0, w4.y, b4.y);
      acc0[i * 4 + 2] = fmaf(at0, w4.z, b4.z);
      acc0[i * 4 + 3] = fmaf(at0, w4.w, b4.w);
      acc1[i * 4 + 0] = fmaf(at1, w4.x, b4.x);
      acc1[i * 4 + 1] = fmaf(at1, w4.y, b4.y);
      acc1[i * 4 + 2] = fmaf(at1, w4.z, b4.z);
      acc1[i * 4 + 3] = fmaf(at1, w4.w, b4.w);
    }
  }
  const float* Ar0 = As + (size_t)n0 * 128;
  const float* Ar1 = As + (size_t)(has1 ? n1 : n0) * 128;
  for (int k4 = 0; k4 < 32; k4++) {
    float a0[4], a1[4];
    *(float4*)a0 = *(const float4*)(Ar0 + (k4 << 2));
    *(float4*)a1 = *(const float4*)(Ar1 + (k4 << 2));
    #pragma unroll
    for (int kk = 0; kk < 4; kk++) {
      const float* wp = WT + (size_t)(1 + (k4 << 2) + kk) * outc + colOff;
      float av0 = a0[kk], av1 = a1[kk];
      #pragma unroll
      for (int i = 0; i < 8; i++) {
        float4 w4 = *(const float4*)(wp + i * 4);
        acc0[i * 4 + 0] = fmaf(av0, w4.x, acc0[i * 4 + 0]);
        acc0[i * 4 + 1] = fmaf(av0, w4.y, acc0[i * 4 + 1]);
        acc0[i * 4 + 2] = fmaf(av0, w4.z, acc0[i * 4 + 2]);
        acc0[i * 4 + 3] = fmaf(av0, w4.w, acc0[i * 4 + 3]);
        acc1[i * 4 + 0] = fmaf(av1, w4.x, acc1[i * 4 + 0]);
        acc1[i * 4 + 1] = fmaf(av1, w4.y, acc1[i * 4 + 1]);
        acc1[i * 4 + 2] = fmaf(av1, w4.z, acc1[i * 4 + 2]);
        acc1[i * 4 + 3] = fmaf(av1, w4.w, acc1[i * 4 + 3]);
      }
    }
  }

  float* sp = cb == 0 ? qo.sp0 : (cb == 1 ? qo.sp1 : qo.sp2);
  float* tp = cb == 0 ? qo.tp0 : (cb == 1 ? qo.tp1 : qo.tp2);
  const int tst = (cb == 0) ? 1 : 2;   // k/v time coords interleave into ktv float2
  const int c0 = grp << 5;
  {
    float ss = 0.f;
    #pragma unroll
    for (int j = 0; j < 32; j++) ss += acc0[j] * acc0[j];
    tp[((size_t)n0 * 4 + grp) * tst] = sqrtf(1.f + ss);
    float* srow = sp + (size_t)n0 * 128 + c0;
    #pragma unroll
    for (int i = 0; i < 8; i++) *(float4*)(srow + i * 4) = *(float4*)&acc0[i * 4];
  }
  if (has1) {
    float ss = 0.f;
    #pragma unroll
    for (int j = 0; j < 32; j++) ss += acc1[j] * acc1[j];
    tp[((size_t)n1 * 4 + grp) * tst] = sqrtf(1.f + ss);
    float* srow = sp + (size_t)n1 * 128 + c0;
    #pragma unroll
    for (int i = 0; i < 8; i++) *(float4*)(srow + i * 4) = *(float4*)&acc1[i * 4];
  }
}

// =================== fused edge attention: 2 nodes/wave, float4 lanes, depth-2 pipeline ===================
// 8 nodes per 256-thread block; one 32-lane half-wave per node.
// lane32 = (head h = lane>>3, d4 = lane&7); each lane holds 4 consecutive dims (float4).
// Gathers for edge j+2 are issued at iteration j (indices prefetched 2 further ahead),
// doubling loads-in-flight vs the depth-1 pipeline. Positions clamped to r1-1 (L2-hot).
__global__ __launch_bounds__(256) void edge_attn_kernel(const int* __restrict__ ro,
                                                        const int* __restrict__ s_csr,
                                                        const float* __restrict__ ebias,
                                                        const float* __restrict__ qs,
                                                        const float* __restrict__ qt,
                                                        const float* __restrict__ ks,
                                                        const float2* __restrict__ ktv,
                                                        const float* __restrict__ vs,
                                                        float* __restrict__ aggS,
                                                        float* __restrict__ aggT) {
  int n = blockIdx.x * 8 + (threadIdx.x >> 5);
  int lane = threadIdx.x & 31;
  int h = lane >> 3, d4 = lane & 7;
  const int fi = (h << 3) + d4;        // float4 index within a 128-float row
  int r0 = ro[n], r1 = ro[n + 1];
  int deg = r1 - r0;

  float4 qq = ((const float4*)(qs + (size_t)n * 128))[fi];
  float qth = qt[(size_t)n * 4 + h];

  float m = -1e30f, den = 0.f, acct = 0.f;
  float4 acc = {0.f, 0.f, 0.f, 0.f};

  if (deg > 0) {
    const int last = r1 - 1;
    // indices for edges 0..3 (clamped)
    int sj0 = s_csr[r0];
    int sj1 = s_csr[min(r0 + 1, last)];
    int s2  = s_csr[min(r0 + 2, last)];
    int s3  = s_csr[min(r0 + 3, last)];
    // data A = edge 0, B = edge 1
    float4 kA = ((const float4*)(ks + (size_t)sj0 * 128))[fi];
    float4 vA = ((const float4*)(vs + (size_t)sj0 * 128))[fi];
    float2 tvA = ktv[(size_t)sj0 * 4 + h];
    float ebA = ebias[(size_t)r0 * 4 + h];
    float4 kB = ((const float4*)(ks + (size_t)sj1 * 128))[fi];
    float4 vB = ((const float4*)(vs + (size_t)sj1 * 128))[fi];
    float2 tvB = ktv[(size_t)sj1 * 4 + h];
    float ebB = ebias[(size_t)min(r0 + 1, last) * 4 + h];

    for (int j = 0; j < deg; j++) {
      float4 k = kA, v = vA;
      float2 tv = tvA;
      float eb = ebA;
      // rotate B -> A, issue loads for edge j+2 with resident index s2
      kA = kB; vA = vB; tvA = tvB; ebA = ebB;
      kB = ((const float4*)(ks + (size_t)s2 * 128))[fi];
      vB = ((const float4*)(vs + (size_t)s2 * 128))[fi];
      tvB = ktv[(size_t)s2 * 4 + h];
      ebB = ebias[(size_t)min(r0 + j + 2, last) * 4 + h];
      s2 = s3;
      s3 = s_csr[min(r0 + j + 4, last)];

      float dp = fmaf(qq.w, k.w, fmaf(qq.z, k.z, fmaf(qq.y, k.y, qq.x * k.x)));
      dp += __shfl_xor(dp, 1);
      dp += __shfl_xor(dp, 2);
      dp += __shfl_xor(dp, 4);
      float sc = fmaf(dp - qth * tv.x, SC_C, eb);   // log2-domain score

      float mN = fmaxf(m, sc);
      float scale = __builtin_amdgcn_exp2f(m - mN);
      float w = __builtin_amdgcn_exp2f(sc - mN);
      den  = den * scale + w;
      acc.x = fmaf(acc.x, scale, w * v.x);
      acc.y = fmaf(acc.y, scale, w * v.y);
      acc.z = fmaf(acc.z, scale, w * v.z);
      acc.w = fmaf(acc.w, scale, w * v.w);
      acct = fmaf(acct, scale, w * tv.y);
      m = mN;
    }
  }

  float inv = 1.f / (den + 1e-16f);
  float4 a = {acc.x * inv, acc.y * inv, acc.z * inv, acc.w * inv};
  float at = acct * inv;
  float p = fmaf(a.w, a.w, fmaf(a.z, a.z, fmaf(a.y, a.y, a.x * a.x)));
  p += __shfl_xor(p, 1);
  p += __shfl_xor(p, 2);
  p += __shfl_xor(p, 4);
  float dh = sqrtf(fmaxf(fabsf(at * at - p), 1e-8f));
  float rdh = 1.f / dh;
  float4 o = {a.x * rdh, a.y * rdh, a.z * rdh, a.w * rdh};
  float q2 = fmaf(o.w, o.w, fmaf(o.z, o.z, fmaf(o.y, o.y, o.x * o.x)));
  q2 += __shfl_xor(q2, 1);
  q2 += __shfl_xor(q2, 2);
  q2 += __shfl_xor(q2, 4);
  q2 += __shfl_xor(q2, 8);
  q2 += __shfl_xor(q2, 16);
  ((float4*)(aggS + (size_t)n * 128))[fi] = o;
  if (lane == 0) aggT[n] = sqrtf(1.f + q2);
}

// =================== launch ===================

extern "C" void kernel_launch(void* const* d_in, const int* in_sizes, int n_in,
                              void* d_out, int out_size, void* d_ws, size_t ws_size,
                              hipStream_t stream) {
  const float* x      = (const float*)d_in[0];
  const int*   ei     = (const int*)  d_in[1];
  const float* ef     = (const float*)d_in[2];
  const float* in_w   = (const float*)d_in[3];
  const float* in_b   = (const float*)d_in[4];
  const float* in_g   = (const float*)d_in[5];
  const float* in_bb  = (const float*)d_in[6];
  const float* q_w    = (const float*)d_in[7];
  const float* q_b    = (const float*)d_in[8];
  const float* k_w    = (const float*)d_in[9];
  const float* k_b    = (const float*)d_in[10];
  const float* v_w    = (const float*)d_in[11];
  const float* v_b    = (const float*)d_in[12];
  const float* out_w  = (const float*)d_in[13];
  const float* out_b  = (const float*)d_in[14];
  const float* eb_w   = (const float*)d_in[15];
  const float* norm_g = (const float*)d_in[16];
  const float* norm_b = (const float*)d_in[17];
  const float* outp_w = (const float*)d_in[18];
  const float* outp_b = (const float*)d_in[19];

  const int* srcI = ei;
  const int* dstI = ei + NE;

  // ---- carve workspace ----
  char* base = (char*)d_ws;
  size_t off = 0;
  auto carve = [&](size_t bytes) -> char* {
    char* p = base + off;
    off = (off + bytes + 255) & ~(size_t)255;
    return p;
  };
  float* hs0    = (float*)carve((size_t)NN * 128 * 4);
  float* ht0    = (float*)carve((size_t)NN * 4);
  float* hs1    = (float*)carve((size_t)NN * 128 * 4);
  float* ht1    = (float*)carve((size_t)NN * 4);
  float* qs     = (float*)carve((size_t)NN * 128 * 4);
  float* qt     = (float*)carve((size_t)NN * 4 * 4);
  float* ks     = (float*)carve((size_t)NN * 128 * 4);
  float* vs     = (float*)carve((size_t)NN * 128 * 4);
  float2* ktv   = (float2*)carve((size_t)NN * 4 * 8);
  float* ebias  = (float*)carve((size_t)2 * NE * 4 * 4);
  int*   s_csr  = (int*)  carve((size_t)NE * 4);
  int*   inv_e  = (int*)  carve((size_t)NE * 4);
  int*   ro     = (int*)  carve((size_t)(NN + 1) * 4);
  int*   counts = (int*)  carve((size_t)NN * 4);
  int*   bsum   = (int*)  carve((size_t)64 * 4);
  int*   boff   = (int*)  carve((size_t)64 * 4);
  float* WT     = (float*)carve((size_t)WT_TOTAL * 4);
  float* bq     = (float*)carve((size_t)768 * 4);
  if (off > ws_size) return;  // workspace too small; bail

  QkvPtrs qkvp{qs, qt, ks, (float*)ktv, vs, (float*)ktv + 1};

  // ---- weight prep ----
  prep_wt<<<(KD * 1280 + 255) / 256, 256, 0, stream>>>(in_w, q_w, k_w, v_w, out_w, outp_w, WT);
  prep_bias<<<3, 256, 0, stream>>>(q_b, k_b, v_b, bq);

  // ---- CSR build (by dst) ----
  constexpr int NB = (NN + 1023) / 1024;   // 40
  zero_i32<<<(NN + 255) / 256, 256, 0, stream>>>(counts, NN);
  count_kernel<<<NE / 256, 256, 0, stream>>>(dstI, counts, NE);
  scan_bsum<<<NB, 1024, 0, stream>>>(counts, bsum);
  scan_boff<<<1, 64, 0, stream>>>(bsum, boff, NB);
  scan_final<<<NB, 1024, 0, stream>>>(counts, boff, ro);
  zero_i32<<<(NN + 255) / 256, 256, 0, stream>>>(counts, NN);
  scatter_kernel<<<NE / 256, 256, 0, stream>>>(srcI, dstI, ro, counts, s_csr, inv_e, NE);

  // ---- edge biases for both layers (CSR-ordered, log2-domain) ----
  ebias_kernel<<<(NE + 255) / 256, 256, 0, stream>>>(ef, eb_w, inv_e, ebias);

  // ---- input embedding ----
  constexpr int NGB = (NN + 127) / 128;    // 313
  expmap_kernel<<<NN / 4, 256, 0, stream>>>(x, hs0, ht0);
  node_gemm<0><<<dim3(NGB, 1), 256, 0, stream>>>(hs0, ht0, WT + OFF_IN, 128, in_b,
                                                 hs0, ht0, nullptr, nullptr,
                                                 in_g, in_bb);

  // ---- layers ----
  float* hcS = hs0; float* hcT = ht0;
  float* hoS = hs1; float* hoT = ht1;
  for (int l = 0; l < 2; l++) {
    qkv_gemm<<<dim3(NGB, 3), 256, 0, stream>>>(
        hcS, hcT, WT + (l ? OFF_QKV1 : OFF_QKV0), bq + l * 384, qkvp);
    edge_attn_kernel<<<NN / 8, 256, 0, stream>>>(ro, s_csr, ebias + (size_t)l * NE * 4,
                                                 qs, qt, ks, ktv, vs, hoS, hoT);
    node_gemm<2><<<dim3(NGB, 1), 256, 0, stream>>>(
        hoS, hoT, WT + (l ? OFF_OUT1 : OFF_OUT0), 128, out_b + l * 128,
        hoS, hoT, hcS, hcT, norm_g + l * 128, norm_b + l * 128);
    float* t;
    t = hcS; hcS = hoS; hoS = t;
    t = hcT; hcT = hoT; hoT = t;
  }

  // ---- output projection + logmap ----
  node_gemm<3><<<dim3(NGB, 1), 256, 0, stream>>>(hcS, hcT, WT + OFF_OUTP, 128, outp_b,
                                                 (float*)d_out, nullptr,
                                                 nullptr, nullptr, nullptr, nullptr);
}

// Round 18
// 503.866 us; speedup vs baseline: 1.2084x; 1.2084x over previous
//
#include <hip/hip_runtime.h>
#include <hip/hip_fp16.h>
#include <math.h>

constexpr int NN = 40000;
constexpr int NE = 640000;
constexpr int KD = 129;     // contraction dim (time + 128 space)

constexpr float LOG2E = 1.4426950408889634f;
constexpr float SC_C  = 0.35355339059327373f * LOG2E;   // 2/sqrt(32) * log2(e)

// ---- transposed-weight buffer offsets (in floats) ----
constexpr int OFF_IN   = 0;
constexpr int OFF_QKV0 = OFF_IN   + KD*128;
constexpr int OFF_QKV1 = OFF_QKV0 + KD*384;
constexpr int OFF_OUT0 = OFF_QKV1 + KD*384;
constexpr int OFF_OUT1 = OFF_OUT0 + KD*128;
constexpr int OFF_OUTP = OFF_OUT1 + KD*128;
constexpr int WT_TOTAL = OFF_OUTP + KD*128;   // 165120 floats

struct QkvPtrs {
  float* qs; float* qt;
  __half* ksh; __half* vsh;
  float* ktv;   // float2 interleaved (kt, vt)
};

struct h4 { __half2 lo, hi; };   // 4 halves = 8 bytes

// =================== small utility kernels ===================

__global__ void zero_i32(int* p, int n) {
  int i = blockIdx.x * 256 + threadIdx.x;
  if (i < n) p[i] = 0;
}

// transpose all weights to k-major once per call
__global__ void prep_wt(const float* __restrict__ in_w, const float* __restrict__ q_w,
                        const float* __restrict__ k_w, const float* __restrict__ v_w,
                        const float* __restrict__ out_w, const float* __restrict__ outp_w,
                        float* __restrict__ WT) {
  int t = blockIdx.x * 256 + threadIdx.x;
  if (t >= KD * 1280) return;
  int k = t / 1280, c = t % 1280;
  float v; int dst;
  if (c < 128) {
    v = in_w[(size_t)c * KD + k];
    dst = OFF_IN + k * 128 + c;
  } else if (c < 896) {
    int l = (c - 128) / 384, cc = (c - 128) % 384;
    int arr = cc >> 7, r = cc & 127;
    const float* w = arr == 0 ? q_w : (arr == 1 ? k_w : v_w);
    v = w[((size_t)l * 128 + r) * KD + k];
    dst = (l == 0 ? OFF_QKV0 : OFF_QKV1) + k * 384 + cc;
  } else if (c < 1152) {
    int l = (c - 896) / 128, r = (c - 896) % 128;
    v = out_w[((size_t)l * 128 + r) * KD + k];
    dst = (l == 0 ? OFF_OUT0 : OFF_OUT1) + k * 128 + r;
  } else {
    int r = c - 1152;
    v = outp_w[(size_t)r * KD + k];
    dst = OFF_OUTP + k * 128 + r;
  }
  WT[dst] = v;
}

__global__ void prep_bias(const float* __restrict__ q_b, const float* __restrict__ k_b,
                          const float* __restrict__ v_b, float* __restrict__ bq) {
  int t = blockIdx.x * 256 + threadIdx.x;
  if (t >= 768) return;
  int l = t / 384, c = t % 384;
  int arr = c >> 7, r = c & 127;
  const float* b = arr == 0 ? q_b : (arr == 1 ? k_b : v_b);
  bq[t] = b[l * 128 + r];
}

// =================== CSR build ===================

__global__ void count_kernel(const int* __restrict__ dst, int* __restrict__ counts, int E) {
  int e = blockIdx.x * 256 + threadIdx.x;
  if (e < E) atomicAdd(&counts[dst[e]], 1);
}

// ---- 3-phase parallel scan ----
__global__ __launch_bounds__(1024) void scan_bsum(const int* __restrict__ counts,
                                                  int* __restrict__ bsum) {
  __shared__ int ws[16];
  int b = blockIdx.x, tid = threadIdx.x;
  int idx = b * 1024 + tid;
  int v = (idx < NN) ? counts[idx] : 0;
  #pragma unroll
  for (int off = 1; off < 64; off <<= 1) v += __shfl_xor(v, off);
  if ((tid & 63) == 0) ws[tid >> 6] = v;
  __syncthreads();
  if (tid < 16) {
    int t = ws[tid];
    #pragma unroll
    for (int off = 1; off < 16; off <<= 1) t += __shfl_xor(t, off);
    if (tid == 0) bsum[b] = t;
  }
}

__global__ void scan_boff(const int* __restrict__ bsum, int* __restrict__ boff, int nb) {
  int tid = threadIdx.x;
  int v = (tid < nb) ? bsum[tid] : 0;
  int s = v;
  #pragma unroll
  for (int off = 1; off < 64; off <<= 1) {
    int t = __shfl_up(s, off);
    if (tid >= off) s += t;
  }
  if (tid < nb) boff[tid] = s - v;   // exclusive
}

__global__ __launch_bounds__(1024) void scan_final(const int* __restrict__ counts,
                                                   const int* __restrict__ boff,
                                                   int* __restrict__ ro) {
  __shared__ int wsum[16];
  int b = blockIdx.x, tid = threadIdx.x, wid = tid >> 6, lane = tid & 63;
  int idx = b * 1024 + tid;
  int v = (idx < NN) ? counts[idx] : 0;
  int s = v;
  #pragma unroll
  for (int off = 1; off < 64; off <<= 1) {
    int t = __shfl_up(s, off);
    if (lane >= off) s += t;
  }
  if (lane == 63) wsum[wid] = s;
  __syncthreads();
  if (wid == 0) {
    int ws = (lane < 16) ? wsum[lane] : 0;
    #pragma unroll
    for (int off = 1; off < 16; off <<= 1) {
      int t = __shfl_up(ws, off);
      if (lane >= off) ws += t;
    }
    if (lane < 16) wsum[lane] = ws;
  }
  __syncthreads();
  int woff = (wid > 0) ? wsum[wid - 1] : 0;
  if (idx < NN) ro[idx + 1] = s + woff + boff[b];
  if (b == 0 && tid == 0) ro[0] = 0;
}

// also emits inv_e: CSR position of each original edge id
__global__ void scatter_kernel(const int* __restrict__ src, const int* __restrict__ dst,
                               const int* __restrict__ ro, int* __restrict__ cursor,
                               int* __restrict__ s_csr, int* __restrict__ inv_e, int E) {
  int e = blockIdx.x * 256 + threadIdx.x;
  if (e >= E) return;
  int d = dst[e];
  int pos = ro[d] + atomicAdd(&cursor[d], 1);
  s_csr[pos] = src[e];
  inv_e[e] = pos;
}

// =================== edge-bias precompute (both layers, CSR-ordered out) ===================
__global__ __launch_bounds__(256) void ebias_kernel(const float* __restrict__ ef,
                                                    const float* __restrict__ ebw,
                                                    const int* __restrict__ inv_e,
                                                    float* __restrict__ eb) {
  __shared__ float w[128];
  if (threadIdx.x < 128) w[threadIdx.x] = ebw[threadIdx.x];
  __syncthreads();
  int e = blockIdx.x * 256 + threadIdx.x;
  if (e >= NE) return;
  float f[16];
  #pragma unroll
  for (int i = 0; i < 4; i++) *(float4*)&f[i * 4] = *(const float4*)(ef + (size_t)e * 16 + i * 4);
  int pos = inv_e[e];
  #pragma unroll
  for (int l = 0; l < 2; l++) {
    float4 o;
    float* op = &o.x;
    #pragma unroll
    for (int h = 0; h < 4; h++) {
      float acc = 0.f;
      #pragma unroll
      for (int i = 0; i < 16; i++) acc = fmaf(f[i], w[l * 64 + h * 16 + i], acc);
      op[h] = fmaf(acc, LOG2E, SC_C);
    }
    *(float4*)(eb + (size_t)l * NE * 4 + (size_t)pos * 4) = o;
  }
}

// =================== expmap0 ===================
__global__ void expmap_kernel(const float* __restrict__ x, float* __restrict__ hs,
                              float* __restrict__ ht) {
  int nl = threadIdx.x >> 6, lane = threadIdx.x & 63;
  int n = blockIdx.x * 4 + nl;
  if (n >= NN) return;
  const float* xr = x + (size_t)n * 128;
  float v0 = xr[lane], v1 = xr[lane + 64];
  float ss = v0 * v0 + v1 * v1;
  #pragma unroll
  for (int off = 1; off < 64; off <<= 1) ss += __shfl_xor(ss, off);
  float nn = sqrtf(fmaxf(ss, 1e-12f));
  float s = sinhf(nn) / nn;
  float* hr = hs + (size_t)n * 128;
  if (lane == 0) ht[n] = coshf(nn);
  hr[lane] = s * v0;
  hr[lane + 64] = s * v1;
}

// =================== node GEMM (EPI 0/2/3): 2 nodes x 32 cols per thread ===================
template<int EPI>
__global__ __launch_bounds__(256, 3) void node_gemm(
    const float* __restrict__ As, const float* __restrict__ At,
    const float* __restrict__ WT, int outc,
    const float* __restrict__ bias,
    float* __restrict__ outS, float* __restrict__ outT,
    const float* __restrict__ resS, const float* __restrict__ resT,
    const float* __restrict__ gv, const float* __restrict__ bvv) {
  __shared__ float red[2][128][5];
  const int tid = threadIdx.x;
  const int ln = tid & 63;
  const int grp = __builtin_amdgcn_readfirstlane(tid >> 6);
  const int n0 = blockIdx.x * 128 + ln;
  const bool has1 = (n0 + 64) < NN;
  const int n1 = has1 ? (n0 + 64) : n0;
  const int c0 = grp << 5;

  float acc0[32], acc1[32];
  { // k = 0 (time row) folded into init together with bias
    float at0 = At[n0];
    float at1 = At[n1];
    const float* w0 = WT + c0;
    #pragma unroll
    for (int i = 0; i < 8; i++) {
      float4 b4 = *(const float4*)(bias + c0 + i * 4);
      float4 w4 = *(const float4*)(w0 + i * 4);
      acc0[i * 4 + 0] = fmaf(at0, w4.x, b4.x);
      acc0[i * 4 + 1] = fmaf(at0, w4.y, b4.y);
      acc0[i * 4 + 2] = fmaf(at0, w4.z, b4.z);
      acc0[i * 4 + 3] = fmaf(at0, w4.w, b4.w);
      acc1[i * 4 + 0] = fmaf(at1, w4.x, b4.x);
      acc1[i * 4 + 1] = fmaf(at1, w4.y, b4.y);
      acc1[i * 4 + 2] = fmaf(at1, w4.z, b4.z);
      acc1[i * 4 + 3] = fmaf(at1, w4.w, b4.w);
    }
  }
  const float* Ar0 = As + (size_t)n0 * 128;
  const float* Ar1 = As + (size_t)n1 * 128;
  for (int k4 = 0; k4 < 32; k4++) {
    float a0[4], a1[4];
    *(float4*)a0 = *(const float4*)(Ar0 + (k4 << 2));
    *(float4*)a1 = *(const float4*)(Ar1 + (k4 << 2));
    #pragma unroll
    for (int kk = 0; kk < 4; kk++) {
      const float* wp = WT + (size_t)(1 + (k4 << 2) + kk) * outc + c0;
      float av0 = a0[kk], av1 = a1[kk];
      #pragma unroll
      for (int i = 0; i < 8; i++) {
        float4 w4 = *(const float4*)(wp + i * 4);
        acc0[i * 4 + 0] = fmaf(av0, w4.x, acc0[i * 4 + 0]);
        acc0[i * 4 + 1] = fmaf(av0, w4.y, acc0[i * 4 + 1]);
        acc0[i * 4 + 2] = fmaf(av0, w4.z, acc0[i * 4 + 2]);
        acc0[i * 4 + 3] = fmaf(av0, w4.w, acc0[i * 4 + 3]);
        acc1[i * 4 + 0] = fmaf(av1, w4.x, acc1[i * 4 + 0]);
        acc1[i * 4 + 1] = fmaf(av1, w4.y, acc1[i * 4 + 1]);
        acc1[i * 4 + 2] = fmaf(av1, w4.z, acc1[i * 4 + 2]);
        acc1[i * 4 + 3] = fmaf(av1, w4.w, acc1[i * 4 + 3]);
      }
    }
  }

  if constexpr (EPI == 0) {           // LayerNorm + ReLU + lift
    float s0 = 0.f, p0 = 0.f, s1 = 0.f, p1 = 0.f;
    #pragma unroll
    for (int j = 0; j < 32; j++) {
      s0 += acc0[j]; p0 += acc0[j] * acc0[j];
      s1 += acc1[j]; p1 += acc1[j] * acc1[j];
    }
    red[0][ln][grp] = s0; red[1][ln][grp] = p0;
    red[0][ln + 64][grp] = s1; red[1][ln + 64][grp] = p1;
    __syncthreads();
    float S0 = 0.f, P0 = 0.f, S1 = 0.f, P1 = 0.f;
    #pragma unroll
    for (int q = 0; q < 4; q++) {
      S0 += red[0][ln][q]; P0 += red[1][ln][q];
      S1 += red[0][ln + 64][q]; P1 += red[1][ln + 64][q];
    }
    float mu0 = S0 * (1.f / 128.f), mu1 = S1 * (1.f / 128.f);
    float rstd0 = 1.f / sqrtf(P0 * (1.f / 128.f) - mu0 * mu0 + 1e-5f);
    float rstd1 = 1.f / sqrtf(P1 * (1.f / 128.f) - mu1 * mu1 + 1e-5f);
    float ss0 = 0.f, ss1 = 0.f;
    #pragma unroll
    for (int j = 0; j < 32; j++) {
      float g = gv[c0 + j], b = bvv[c0 + j];
      float z0 = fmaxf((acc0[j] - mu0) * rstd0 * g + b, 0.f);
      float z1 = fmaxf((acc1[j] - mu1) * rstd1 * g + b, 0.f);
      ss0 += z0 * z0; ss1 += z1 * z1;
      acc0[j] = z0; acc1[j] = z1;
    }
    __syncthreads();
    red[0][ln][grp] = ss0; red[0][ln + 64][grp] = ss1;
    __syncthreads();
    float SS0 = red[0][ln][0] + red[0][ln][1] + red[0][ln][2] + red[0][ln][3];
    float SS1 = red[0][ln + 64][0] + red[0][ln + 64][1] + red[0][ln + 64][2] + red[0][ln + 64][3];
    float* o0 = outS + (size_t)n0 * 128 + c0;
    #pragma unroll
    for (int i = 0; i < 8; i++) *(float4*)(o0 + i * 4) = *(float4*)&acc0[i * 4];
    if (grp == 0) outT[n0] = sqrtf(1.f + SS0);
    if (has1) {
      float* o1 = outS + (size_t)n1 * 128 + c0;
      #pragma unroll
      for (int i = 0; i < 8; i++) *(float4*)(o1 + i * 4) = *(float4*)&acc1[i * 4];
      if (grp == 0) outT[n1] = sqrtf(1.f + SS1);
    }
  } else if constexpr (EPI == 2) {    // lift + midpoint2(res) + LayerNorm + lift
    float sy0 = 0.f, sy1 = 0.f;
    #pragma unroll
    for (int j = 0; j < 32; j++) { sy0 += acc0[j] * acc0[j]; sy1 += acc1[j] * acc1[j]; }
    red[0][ln][grp] = sy0; red[0][ln + 64][grp] = sy1;
    __syncthreads();
    float SY0 = red[0][ln][0] + red[0][ln][1] + red[0][ln][2] + red[0][ln][3];
    float SY1 = red[0][ln + 64][0] + red[0][ln + 64][1] + red[0][ln + 64][2] + red[0][ln + 64][3];
    float a00 = 0.5f * (sqrtf(1.f + SY0) + resT[n0]);
    float a01 = 0.5f * (sqrtf(1.f + SY1) + resT[n1]);
    const float* rr0 = resS + (size_t)n0 * 128 + c0;
    const float* rr1 = resS + (size_t)n1 * 128 + c0;
    float sa0 = 0.f, su0 = 0.f, sa1 = 0.f, su1 = 0.f;
    #pragma unroll
    for (int i = 0; i < 8; i++) {
      float4 r40 = *(const float4*)(rr0 + i * 4);
      float4 r41 = *(const float4*)(rr1 + i * 4);
      const float* rp0 = &r40.x;
      const float* rp1 = &r41.x;
      #pragma unroll
      for (int q = 0; q < 4; q++) {
        float a = 0.5f * (acc0[i * 4 + q] + rp0[q]);
        acc0[i * 4 + q] = a; sa0 += a * a; su0 += a;
        float b = 0.5f * (acc1[i * 4 + q] + rp1[q]);
        acc1[i * 4 + q] = b; sa1 += b * b; su1 += b;
      }
    }
    __syncthreads();
    red[0][ln][grp] = sa0; red[1][ln][grp] = su0;
    red[0][ln + 64][grp] = sa1; red[1][ln + 64][grp] = su1;
    __syncthreads();
    float SA0 = 0.f, SU0 = 0.f, SA1 = 0.f, SU1 = 0.f;
    #pragma unroll
    for (int q = 0; q < 4; q++) {
      SA0 += red[0][ln][q]; SU0 += red[1][ln][q];
      SA1 += red[0][ln + 64][q]; SU1 += red[1][ln + 64][q];
    }
    float inv0 = 1.f / sqrtf(fmaxf(fabsf(a00 * a00 - SA0), 1e-8f));
    float inv1 = 1.f / sqrtf(fmaxf(fabsf(a01 * a01 - SA1), 1e-8f));
    float mu0 = SU0 * inv0 * (1.f / 128.f), mu1 = SU1 * inv1 * (1.f / 128.f);
    float rstd0 = 1.f / sqrtf(SA0 * inv0 * inv0 * (1.f / 128.f) - mu0 * mu0 + 1e-5f);
    float rstd1 = 1.f / sqrtf(SA1 * inv1 * inv1 * (1.f / 128.f) - mu1 * mu1 + 1e-5f);
    float ss0 = 0.f, ss1 = 0.f;
    #pragma unroll
    for (int j = 0; j < 32; j++) {
      float g = gv[c0 + j], b = bvv[c0 + j];
      float z0 = (acc0[j] * inv0 - mu0) * rstd0 * g + b;
      float z1 = (acc1[j] * inv1 - mu1) * rstd1 * g + b;
      ss0 += z0 * z0; ss1 += z1 * z1;
      acc0[j] = z0; acc1[j] = z1;
    }
    __syncthreads();
    red[0][ln][grp] = ss0; red[0][ln + 64][grp] = ss1;
    __syncthreads();
    float SS0 = red[0][ln][0] + red[0][ln][1] + red[0][ln][2] + red[0][ln][3];
    float SS1 = red[0][ln + 64][0] + red[0][ln + 64][1] + red[0][ln + 64][2] + red[0][ln + 64][3];
    float* o0 = outS + (size_t)n0 * 128 + c0;
    #pragma unroll
    for (int i = 0; i < 8; i++) *(float4*)(o0 + i * 4) = *(float4*)&acc0[i * 4];
    if (grp == 0) outT[n0] = sqrtf(1.f + SS0);
    if (has1) {
      float* o1 = outS + (size_t)n1 * 128 + c0;
      #pragma unroll
      for (int i = 0; i < 8; i++) *(float4*)(o1 + i * 4) = *(float4*)&acc1[i * 4];
      if (grp == 0) outT[n1] = sqrtf(1.f + SS1);
    }
  } else {                            // EPI == 3: lift + logmap0 (packed out)
    float s0 = 0.f, s1 = 0.f;
    #pragma unroll
    for (int j = 0; j < 32; j++) { s0 += acc0[j] * acc0[j]; s1 += acc1[j] * acc1[j]; }
    red[0][ln][grp] = s0; red[0][ln + 64][grp] = s1;
    __syncthreads();
    float S0 = red[0][ln][0] + red[0][ln][1] + red[0][ln][2] + red[0][ln][3];
    float S1 = red[0][ln + 64][0] + red[0][ln + 64][1] + red[0][ln + 64][2] + red[0][ln + 64][3];
    float nn0 = sqrtf(fmaxf(S0, 1e-12f));
    float nn1 = sqrtf(fmaxf(S1, 1e-12f));
    float sc0 = acoshf(fmaxf(sqrtf(1.f + S0), 1.f + 1e-7f)) / nn0;
    float sc1 = acoshf(fmaxf(sqrtf(1.f + S1), 1.f + 1e-7f)) / nn1;
    float* o0 = outS + (size_t)n0 * 128 + c0;
    #pragma unroll
    for (int j = 0; j < 32; j++) { acc0[j] *= sc0; acc1[j] *= sc1; }
    #pragma unroll
    for (int i = 0; i < 8; i++) *(float4*)(o0 + i * 4) = *(float4*)&acc0[i * 4];
    if (has1) {
      float* o1 = outS + (size_t)n1 * 128 + c0;
      #pragma unroll
      for (int i = 0; i < 8; i++) *(float4*)(o1 + i * 4) = *(float4*)&acc1[i * 4];
    }
  }
}

// =================== qkv GEMM: 2 nodes x 32 cols per thread; k/v stored fp16 ===================
__global__ __launch_bounds__(256, 3) void qkv_gemm(
    const float* __restrict__ As, const float* __restrict__ At,
    const float* __restrict__ WT, const float* __restrict__ bias,
    QkvPtrs qo) {
  const int tid = threadIdx.x;
  const int ln = tid & 63;
  const int grp = __builtin_amdgcn_readfirstlane(tid >> 6);
  const int n0 = blockIdx.x * 128 + ln;
  const int n1 = n0 + 64;
  const bool has1 = n1 < NN;
  const int cb = blockIdx.y;
  const int colOff = (cb << 7) + (grp << 5);
  constexpr int outc = 384;

  float acc0[32], acc1[32];
  {
    float at0 = At[n0];
    float at1 = has1 ? At[n1] : 0.f;
    const float* w0 = WT + colOff;
    #pragma unroll
    for (int i = 0; i < 8; i++) {
      float4 b4 = *(const float4*)(bias + colOff + i * 4);
      float4 w4 = *(const float4*)(w0 + i * 4);
      acc0[i * 4 + 0] = fmaf(at0, w4.x, b4.x);
      acc0[i * 4 + 1] = fmaf(at0, w4.y, b4.y);
      acc0[i * 4 + 2] = fmaf(at0, w4.z, b4.z);
      acc0[i * 4 + 3] = fmaf(at0, w4.w, b4.w);
      acc1[i * 4 + 0] = fmaf(at1, w4.x, b4.x);
      acc1[i * 4 + 1] = fmaf(at1, w4.y, b4.y);
      acc1[i * 4 + 2] = fmaf(at1, w4.z, b4.z);
      acc1[i * 4 + 3] = fmaf(at1, w4.w, b4.w);
    }
  }
  const float* Ar0 = As + (size_t)n0 * 128;
  const float* Ar1 = As + (size_t)(has1 ? n1 : n0) * 128;
  for (int k4 = 0; k4 < 32; k4++) {
    float a0[4], a1[4];
    *(float4*)a0 = *(const float4*)(Ar0 + (k4 << 2));
    *(float4*)a1 = *(const float4*)(Ar1 + (k4 << 2));
    #pragma unroll
    for (int kk = 0; kk < 4; kk++) {
      const float* wp = WT + (size_t)(1 + (k4 << 2) + kk) * outc + colOff;
      float av0 = a0[kk], av1 = a1[kk];
      #pragma unroll
      for (int i = 0; i < 8; i++) {
        float4 w4 = *(const float4*)(wp + i * 4);
        acc0[i * 4 + 0] = fmaf(av0, w4.x, acc0[i * 4 + 0]);
        acc0[i * 4 + 1] = fmaf(av0, w4.y, acc0[i * 4 + 1]);
        acc0[i * 4 + 2] = fmaf(av0, w4.z, acc0[i * 4 + 2]);
        acc0[i * 4 + 3] = fmaf(av0, w4.w, acc0[i * 4 + 3]);
        acc1[i * 4 + 0] = fmaf(av1, w4.x, acc1[i * 4 + 0]);
        acc1[i * 4 + 1] = fmaf(av1, w4.y, acc1[i * 4 + 1]);
        acc1[i * 4 + 2] = fmaf(av1, w4.z, acc1[i * 4 + 2]);
        acc1[i * 4 + 3] = fmaf(av1, w4.w, acc1[i * 4 + 3]);
      }
    }
  }

  const int c0 = grp << 5;
  // time coordinate (lift): qt for q; ktv interleaved float2 for k/v
  {
    float ss = 0.f;
    #pragma unroll
    for (int j = 0; j < 32; j++) ss += acc0[j] * acc0[j];
    float tv = sqrtf(1.f + ss);
    if (cb == 0) qo.qt[(size_t)n0 * 4 + grp] = tv;
    else qo.ktv[((size_t)n0 * 4 + grp) * 2 + (cb - 1)] = tv;
  }
  if (has1) {
    float ss = 0.f;
    #pragma unroll
    for (int j = 0; j < 32; j++) ss += acc1[j] * acc1[j];
    float tv = sqrtf(1.f + ss);
    if (cb == 0) qo.qt[(size_t)n1 * 4 + grp] = tv;
    else qo.ktv[((size_t)n1 * 4 + grp) * 2 + (cb - 1)] = tv;
  }
  // space components
  if (cb == 0) {
    float* srow = qo.qs + (size_t)n0 * 128 + c0;
    #pragma unroll
    for (int i = 0; i < 8; i++) *(float4*)(srow + i * 4) = *(float4*)&acc0[i * 4];
    if (has1) {
      float* srow1 = qo.qs + (size_t)n1 * 128 + c0;
      #pragma unroll
      for (int i = 0; i < 8; i++) *(float4*)(srow1 + i * 4) = *(float4*)&acc1[i * 4];
    }
  } else {
    __half* hb = (cb == 1 ? qo.ksh : qo.vsh);
    __half2* hrow = (__half2*)(hb + (size_t)n0 * 128 + c0);
    #pragma unroll
    for (int j = 0; j < 16; j++) hrow[j] = __floats2half2_rn(acc0[2 * j], acc0[2 * j + 1]);
    if (has1) {
      __half2* hrow1 = (__half2*)(hb + (size_t)n1 * 128 + c0);
      #pragma unroll
      for (int j = 0; j < 16; j++) hrow1[j] = __floats2half2_rn(acc1[2 * j], acc1[2 * j + 1]);
    }
  }
}

// =================== fused edge attention: 2 nodes/wave, fp16 k/v gathers ===================
// 8 nodes per 256-thread block; one 32-lane half-wave per node.
// lane32 = (head h = lane>>3, d4 = lane&7); each lane holds 4 consecutive dims.
// k/v gathered as 8B fp16x4 (half the traffic of f32); math in f32.
__global__ __launch_bounds__(256) void edge_attn_kernel(const int* __restrict__ ro,
                                                        const int* __restrict__ s_csr,
                                                        const float* __restrict__ ebias,
                                                        const float* __restrict__ qs,
                                                        const float* __restrict__ qt,
                                                        const __half* __restrict__ ksh,
                                                        const float2* __restrict__ ktv,
                                                        const __half* __restrict__ vsh,
                                                        float* __restrict__ aggS,
                                                        float* __restrict__ aggT) {
  int n = blockIdx.x * 8 + (threadIdx.x >> 5);
  int lane = threadIdx.x & 31;
  int h = lane >> 3, d4 = lane & 7;
  const int fi = (h << 3) + d4;        // 8B group index within a 128-elem row
  int r0 = ro[n], deg = ro[n + 1] - r0;

  float4 qq = ((const float4*)(qs + (size_t)n * 128))[fi];
  float qth = qt[(size_t)n * 4 + h];

  const h4* kp4 = (const h4*)ksh;
  const h4* vp4 = (const h4*)vsh;

  float m = -1e30f, den = 0.f, acct = 0.f;
  float4 acc = {0.f, 0.f, 0.f, 0.f};

  // pipeline regs (next edge)
  h4 kN, vN;
  kN.lo = __floats2half2_rn(0.f, 0.f); kN.hi = kN.lo;
  vN = kN;
  float2 tvN = {0.f, 0.f};
  float ebN = 0.f;
  if (deg > 0) {
    int sN = s_csr[r0];
    kN = kp4[(size_t)sN * 32 + fi];
    vN = vp4[(size_t)sN * 32 + fi];
    tvN = ktv[(size_t)sN * 4 + h];
    ebN = ebias[(size_t)r0 * 4 + h];
  }
  int s1 = (deg > 1) ? s_csr[r0 + 1] : 0;

  for (int j = 0; j < deg; j++) {
    h4 kh = kN, vh = vN;
    float2 tv = tvN;
    float eb = ebN;
    if (j + 1 < deg) {
      kN = kp4[(size_t)s1 * 32 + fi];
      vN = vp4[(size_t)s1 * 32 + fi];
      tvN = ktv[(size_t)s1 * 4 + h];
      ebN = ebias[(size_t)(r0 + j + 1) * 4 + h];
    }
    if (j + 2 < deg) s1 = s_csr[r0 + j + 2];

    float2 kl = __half22float2(kh.lo), kh2 = __half22float2(kh.hi);
    float dp = fmaf(kh2.y, qq.w, fmaf(kh2.x, qq.z, fmaf(kl.y, qq.y, kl.x * qq.x)));
    dp += __shfl_xor(dp, 1);
    dp += __shfl_xor(dp, 2);
    dp += __shfl_xor(dp, 4);
    float sc = fmaf(dp - qth * tv.x, SC_C, eb);   // log2-domain score

    float mN = fmaxf(m, sc);
    float scale = __builtin_amdgcn_exp2f(m - mN);
    float w = __builtin_amdgcn_exp2f(sc - mN);
    float2 vl = __half22float2(vh.lo), vh2 = __half22float2(vh.hi);
    den  = den * scale + w;
    acc.x = fmaf(acc.x, scale, w * vl.x);
    acc.y = fmaf(acc.y, scale, w * vl.y);
    acc.z = fmaf(acc.z, scale, w * vh2.x);
    acc.w = fmaf(acc.w, scale, w * vh2.y);
    acct = fmaf(acct, scale, w * tv.y);
    m = mN;
  }

  float inv = 1.f / (den + 1e-16f);
  float4 a = {acc.x * inv, acc.y * inv, acc.z * inv, acc.w * inv};
  float at = acct * inv;
  float p = fmaf(a.w, a.w, fmaf(a.z, a.z, fmaf(a.y, a.y, a.x * a.x)));
  p += __shfl_xor(p, 1);
  p += __shfl_xor(p, 2);
  p += __shfl_xor(p, 4);
  float dh = sqrtf(fmaxf(fabsf(at * at - p), 1e-8f));
  float rdh = 1.f / dh;
  float4 o = {a.x * rdh, a.y * rdh, a.z * rdh, a.w * rdh};
  float q2 = fmaf(o.w, o.w, fmaf(o.z, o.z, fmaf(o.y, o.y, o.x * o.x)));
  q2 += __shfl_xor(q2, 1);
  q2 += __shfl_xor(q2, 2);
  q2 += __shfl_xor(q2, 4);
  q2 += __shfl_xor(q2, 8);
  q2 += __shfl_xor(q2, 16);
  ((float4*)(aggS + (size_t)n * 128))[fi] = o;
  if (lane == 0) aggT[n] = sqrtf(1.f + q2);
}

// =================== launch ===================

extern "C" void kernel_launch(void* const* d_in, const int* in_sizes, int n_in,
                              void* d_out, int out_size, void* d_ws, size_t ws_size,
                              hipStream_t stream) {
  const float* x      = (const float*)d_in[0];
  const int*   ei     = (const int*)  d_in[1];
  const float* ef     = (const float*)d_in[2];
  const float* in_w   = (const float*)d_in[3];
  const float* in_b   = (const float*)d_in[4];
  const float* in_g   = (const float*)d_in[5];
  const float* in_bb  = (const float*)d_in[6];
  const float* q_w    = (const float*)d_in[7];
  const float* q_b    = (const float*)d_in[8];
  const float* k_w    = (const float*)d_in[9];
  const float* k_b    = (const float*)d_in[10];
  const float* v_w    = (const float*)d_in[11];
  const float* v_b    = (const float*)d_in[12];
  const float* out_w  = (const float*)d_in[13];
  const float* out_b  = (const float*)d_in[14];
  const float* eb_w   = (const float*)d_in[15];
  const float* norm_g = (const float*)d_in[16];
  const float* norm_b = (const float*)d_in[17];
  const float* outp_w = (const float*)d_in[18];
  const float* outp_b = (const float*)d_in[19];

  const int* srcI = ei;
  const int* dstI = ei + NE;

  // ---- carve workspace ----
  char* base = (char*)d_ws;
  size_t off = 0;
  auto carve = [&](size_t bytes) -> char* {
    char* p = base + off;
    off = (off + bytes + 255) & ~(size_t)255;
    return p;
  };
  float* hs0    = (float*)carve((size_t)NN * 128 * 4);
  float* ht0    = (float*)carve((size_t)NN * 4);
  float* hs1    = (float*)carve((size_t)NN * 128 * 4);
  float* ht1    = (float*)carve((size_t)NN * 4);
  float* qs     = (float*)carve((size_t)NN * 128 * 4);
  float* qt     = (float*)carve((size_t)NN * 4 * 4);
  __half* ksh   = (__half*)carve((size_t)NN * 128 * 2);
  __half* vsh   = (__half*)carve((size_t)NN * 128 * 2);
  float* ktv    = (float*)carve((size_t)NN * 4 * 8);
  float* ebias  = (float*)carve((size_t)2 * NE * 4 * 4);
  int*   s_csr  = (int*)  carve((size_t)NE * 4);
  int*   inv_e  = (int*)  carve((size_t)NE * 4);
  int*   ro     = (int*)  carve((size_t)(NN + 1) * 4);
  int*   counts = (int*)  carve((size_t)NN * 4);
  int*   bsum   = (int*)  carve((size_t)64 * 4);
  int*   boff   = (int*)  carve((size_t)64 * 4);
  float* WT     = (float*)carve((size_t)WT_TOTAL * 4);
  float* bq     = (float*)carve((size_t)768 * 4);
  if (off > ws_size) return;  // workspace too small; bail

  QkvPtrs qkvp{qs, qt, ksh, vsh, ktv};

  // ---- weight prep ----
  prep_wt<<<(KD * 1280 + 255) / 256, 256, 0, stream>>>(in_w, q_w, k_w, v_w, out_w, outp_w, WT);
  prep_bias<<<3, 256, 0, stream>>>(q_b, k_b, v_b, bq);

  // ---- CSR build (by dst) ----
  constexpr int NB = (NN + 1023) / 1024;   // 40
  zero_i32<<<(NN + 255) / 256, 256, 0, stream>>>(counts, NN);
  count_kernel<<<NE / 256, 256, 0, stream>>>(dstI, counts, NE);
  scan_bsum<<<NB, 1024, 0, stream>>>(counts, bsum);
  scan_boff<<<1, 64, 0, stream>>>(bsum, boff, NB);
  scan_final<<<NB, 1024, 0, stream>>>(counts, boff, ro);
  zero_i32<<<(NN + 255) / 256, 256, 0, stream>>>(counts, NN);
  scatter_kernel<<<NE / 256, 256, 0, stream>>>(srcI, dstI, ro, counts, s_csr, inv_e, NE);

  // ---- edge biases for both layers (CSR-ordered, log2-domain) ----
  ebias_kernel<<<(NE + 255) / 256, 256, 0, stream>>>(ef, eb_w, inv_e, ebias);

  // ---- input embedding ----
  constexpr int NGB = (NN + 127) / 128;    // 313
  expmap_kernel<<<NN / 4, 256, 0, stream>>>(x, hs0, ht0);
  node_gemm<0><<<dim3(NGB, 1), 256, 0, stream>>>(hs0, ht0, WT + OFF_IN, 128, in_b,
                                                 hs0, ht0, nullptr, nullptr,
                                                 in_g, in_bb);

  // ---- layers ----
  float* hcS = hs0; float* hcT = ht0;
  float* hoS = hs1; float* hoT = ht1;
  for (int l = 0; l < 2; l++) {
    qkv_gemm<<<dim3(NGB, 3), 256, 0, stream>>>(
        hcS, hcT, WT + (l ? OFF_QKV1 : OFF_QKV0), bq + l * 384, qkvp);
    edge_attn_kernel<<<NN / 8, 256, 0, stream>>>(ro, s_csr, ebias + (size_t)l * NE * 4,
                                                 qs, qt, ksh, (const float2*)ktv, vsh,
                                                 hoS, hoT);
    node_gemm<2><<<dim3(NGB, 1), 256, 0, stream>>>(
        hoS, hoT, WT + (l ? OFF_OUT1 : OFF_OUT0), 128, out_b + l * 128,
        hoS, hoT, hcS, hcT, norm_g + l * 128, norm_b + l * 128);
    float* t;
    t = hcS; hcS = hoS; hoS = t;
    t = hcT; hcT = hoT; hoT = t;
  }

  // ---- output projection + logmap ----
  node_gemm<3><<<dim3(NGB, 1), 256, 0, stream>>>(hcS, hcT, WT + OFF_OUTP, 128, outp_b,
                                                 (float*)d_out, nullptr,
                                                 nullptr, nullptr, nullptr, nullptr);
}